// Round 12
// baseline (82.328 us; speedup 1.0000x reference)
//
#include <hip/hip_runtime.h>
#include <math.h>

#define BB 8
#define NN 512
#define FF 32
#define HH 64
#define NEG_BIG (-1.0e30f)

__device__ __forceinline__ float lane_bcast(float v, int l) {
    return __int_as_float(__builtin_amdgcn_readlane(__float_as_int(v), l));
}

// ---------------------------------------------------------------------------
// encode: h = relu(x@W_enc+b); zi = h@W_e1[:H]+b_e1 (folded); zjT2 = the
// second projection stored TRANSPOSED + k-pair-interleaved: float2 at
// [b][k>>1][n] = (z[2k'], z[2k'+1]) so the edge loop loads 8B/lane coalesced
// and can use packed fp32 math.
// ---------------------------------------------------------------------------
__global__ __launch_bounds__(256) void encode_kernel(
    const float* __restrict__ x, const float* __restrict__ W_enc,
    const float* __restrict__ b_enc, const float* __restrict__ W_e1,
    const float* __restrict__ b_e1,
    float* __restrict__ h, float* __restrict__ zi, float* __restrict__ zjT2)
{
    const int t = threadIdx.x;
    const int hh = t & 63;
    const int qu = __builtin_amdgcn_readfirstlane(t >> 6);
    const int gR = blockIdx.x * 4 + qu;           // 0..B*N-1

    const float xv = x[gR * FF + (hh & 31)];      // coalesced; lanes 32+ dup
    float acc = b_enc[hh];
#pragma unroll 8
    for (int k = 0; k < FF; ++k)
        acc = fmaf(lane_bcast(xv, k), W_enc[k * HH + hh], acc);
    const float hval = fmaxf(acc, 0.f);
    h[gR * HH + hh] = hval;

    float z1 = b_e1[hh], z2 = 0.f;
#pragma unroll 8
    for (int k = 0; k < HH; ++k) {
        const float hk = lane_bcast(hval, k);
        z1 = fmaf(hk, W_e1[k * HH + hh], z1);
        z2 = fmaf(hk, W_e1[(HH + k) * HH + hh], z2);
    }
    zi[gR * HH + hh] = z1;
    // zjT2[b][hh>>1][n].comp(hh&1)
    const int b = gR >> 9, n = gR & (NN - 1);
    zjT2[(((size_t)b * 32 + (hh >> 1)) * NN + n) * 2 + (hh & 1)] = z2;
}

// ---------------------------------------------------------------------------
// adjlayer<MODE>: 1024 blocks x 256 thr, launch_bounds(256,4) -> 4 blocks/CU.
// block = (b, 4 rows); wave w: edge/A j-slice [128w,128w+128) (lane tj holds
// j0=128w+tj, j1=j0+64), then OWNS row w end-to-end (B, C, GRU) -- phases
// B..finalize are barrier-free and LDS-free (readlane broadcasts only).
// MODE 0: edge logits (packed-fp32 float2 k-pair loop, zi/W_e2 via s_load)
//         + softmax -> va regs + adjw store.
// MODE 1: va loaded from adjw; readout partial folded at the end.
// Barriers: MODE0 = 3 (softmax x2, RED), MODE1 = 2 (RED, hsum).
// ---------------------------------------------------------------------------
template <int MODE>
__global__ __launch_bounds__(256, 4) void adjlayer_kernel(
    const float* __restrict__ zi, const float* __restrict__ zjT2,
    const float* __restrict__ We2, const float* __restrict__ be2,
    float* __restrict__ adjw, const float* __restrict__ h_in,
    const float* __restrict__ Wmsg, const float* __restrict__ bmsg,
    const float* __restrict__ Wih, const float* __restrict__ bih,
    const float* __restrict__ Whh, const float* __restrict__ bhh,
    float* __restrict__ h_out, float* __restrict__ partial)
{
    const int b  = blockIdx.x >> 7;               // 1024 = 8 b x 128 tiles
    const int i0 = (blockIdx.x & 127) << 2;       // 4 rows
    const int t  = threadIdx.x;
    const int tj = t & 63;
    const int w  = __builtin_amdgcn_readfirstlane(t >> 6);   // 0..3
    const int gR0 = b * NN + i0;

    __shared__ float RED[4][4][66];               // A partials [wave][row][c]
    __shared__ float redm[4][4], reds[4][4];
    __shared__ float hsum[4][66];                 // MODE1 readout partial

    // own-row h, kept per-lane (lane = column c); broadcast later via readlane
    const float hreg = h_in[(size_t)(gR0 + w) * HH + tj];

    //=== adjacency slice in registers: va[r][u] = adj[i0+r][128w+64u+tj] ====
    float va[4][2];
    if (MODE == 0) {
        const float2* zi2 = (const float2*)(zi + (size_t)gR0 * HH);  // s_load
        const float2* we2 = (const float2*)We2;                      // s_load
        const float2* zt2 = (const float2*)zjT2 + (size_t)b * 32 * NN;
        const int j0 = 128 * w + tj, j1 = j0 + 64;

        float2 a2[4][2];
#pragma unroll
        for (int r = 0; r < 4; ++r) {
            a2[r][0] = make_float2(0.f, 0.f);
            a2[r][1] = make_float2(0.f, 0.f);
        }
#pragma unroll 8
        for (int k2 = 0; k2 < 32; ++k2) {
            const float2 z0 = zt2[(size_t)k2 * NN + j0];   // 8B coalesced
            const float2 z1 = zt2[(size_t)k2 * NN + j1];
            const float2 wk = we2[k2];                     // s_load
#pragma unroll
            for (int r = 0; r < 4; ++r) {
                const float2 zv = zi2[r * 32 + k2];        // s_load
                a2[r][0].x = fmaf(fmaxf(zv.x + z0.x, 0.f), wk.x, a2[r][0].x);
                a2[r][0].y = fmaf(fmaxf(zv.y + z0.y, 0.f), wk.y, a2[r][0].y);
                a2[r][1].x = fmaf(fmaxf(zv.x + z1.x, 0.f), wk.x, a2[r][1].x);
                a2[r][1].y = fmaf(fmaxf(zv.y + z1.y, 0.f), wk.y, a2[r][1].y);
            }
        }
        const float bias2 = be2[0];
        float acc[4][2];
#pragma unroll
        for (int r = 0; r < 4; ++r) {
            acc[r][0] = a2[r][0].x + a2[r][0].y + bias2;
            acc[r][1] = a2[r][1].x + a2[r][1].y + bias2;
            if (j0 == i0 + r) acc[r][0] = NEG_BIG;         // diag mask
            if (j1 == i0 + r) acc[r][1] = NEG_BIG;
        }

        // softmax over j (cross-wave: 4 j-slices)
#pragma unroll
        for (int r = 0; r < 4; ++r) {
            float m = fmaxf(acc[r][0], acc[r][1]);
#pragma unroll
            for (int off = 32; off >= 1; off >>= 1)
                m = fmaxf(m, __shfl_xor(m, off));
            if (tj == 0) redm[w][r] = m;
        }
        __syncthreads();
        float M[4];
#pragma unroll
        for (int r = 0; r < 4; ++r)
            M[r] = fmaxf(fmaxf(redm[0][r], redm[1][r]),
                         fmaxf(redm[2][r], redm[3][r]));
#pragma unroll
        for (int r = 0; r < 4; ++r) {
            va[r][0] = __expf(acc[r][0] - M[r]);
            va[r][1] = __expf(acc[r][1] - M[r]);
            float s = va[r][0] + va[r][1];
#pragma unroll
            for (int off = 32; off >= 1; off >>= 1) s += __shfl_xor(s, off);
            if (tj == 0) reds[w][r] = s;
        }
        __syncthreads();
#pragma unroll
        for (int r = 0; r < 4; ++r) {
            const float inv = 1.0f /
                (reds[0][r] + reds[1][r] + reds[2][r] + reds[3][r]);
            va[r][0] *= inv; va[r][1] *= inv;
            adjw[(size_t)(gR0 + r) * NN + j0] = va[r][0];
            adjw[(size_t)(gR0 + r) * NN + j1] = va[r][1];
        }
    } else {
        const int j0 = 128 * w + tj;
#pragma unroll
        for (int r = 0; r < 4; ++r) {
            va[r][0] = adjw[(size_t)(gR0 + r) * NN + j0];
            va[r][1] = adjw[(size_t)(gR0 + r) * NN + j0 + 64];
        }
    }

    //=== phase A: m partials over this wave's 128-j slice (lane = c) ========
    {
        const float* hq = h_in + ((size_t)b * NN + 128 * w) * HH + tj;
        float mac[4] = {0.f, 0.f, 0.f, 0.f};
#pragma unroll 4
        for (int jj = 0; jj < 64; ++jj) {
            const float hv0 = hq[(size_t)jj * HH];
            const float hv1 = hq[(size_t)(jj + 64) * HH];
#pragma unroll
            for (int r = 0; r < 4; ++r) {
                mac[r] = fmaf(lane_bcast(va[r][0], jj), hv0, mac[r]);
                mac[r] = fmaf(lane_bcast(va[r][1], jj), hv1, mac[r]);
            }
        }
#pragma unroll
        for (int r = 0; r < 4; ++r) RED[w][r][tj] = mac[r];
    }
    __syncthreads();

    //=== phases B..finalize: wave w owns row w, no barriers, no LDS =========
    // B: m reduce + mm = relu(m @ Wmsg + bmsg)
    const float m = RED[0][w][tj] + RED[1][w][tj] + RED[2][w][tj] + RED[3][w][tj];
    float mmv = bmsg[tj];
#pragma unroll 8
    for (int k = 0; k < HH; ++k)
        mmv = fmaf(lane_bcast(m, k), Wmsg[k * HH + tj], mmv);
    mmv = fmaxf(mmv, 0.f);

    // C: all 6 gates for own row (mm via readlane, h via readlane of hreg)
    float g0 = bih[tj], g1 = bih[64 + tj], g2 = bih[128 + tj];
    float g3 = bhh[tj], g4 = bhh[64 + tj], g5 = bhh[128 + tj];
#pragma unroll 4
    for (int k = 0; k < HH; ++k) {
        const float smm = lane_bcast(mmv, k);
        const float sh  = lane_bcast(hreg, k);
        const float* wi = Wih + (size_t)k * 192;
        const float* wh = Whh + (size_t)k * 192;
        g0 = fmaf(smm, wi[tj], g0);
        g1 = fmaf(smm, wi[64 + tj], g1);
        g2 = fmaf(smm, wi[128 + tj], g2);
        g3 = fmaf(sh, wh[tj], g3);
        g4 = fmaf(sh, wh[64 + tj], g4);
        g5 = fmaf(sh, wh[128 + tj], g5);
    }
    const float rg = 1.f / (1.f + __expf(-(g0 + g3)));
    const float zg = 1.f / (1.f + __expf(-(g1 + g4)));
    const float ng = tanhf(g2 + rg * g5);
    const float hnew = (1.f - zg) * ng + zg * hreg;
    h_out[(size_t)(gR0 + w) * HH + tj] = hnew;

    if (MODE == 1) {   // readout partial: block sum of its 4 rows
        hsum[w][tj] = hnew;
        __syncthreads();
        if (w == 0) {
            partial[blockIdx.x * 64 + tj] =
                hsum[0][tj] + hsum[1][tj] + hsum[2][tj] + hsum[3][tj];
        }
    }
}

// ---------------------------------------------------------------------------
// readout: out[b] = (sum of 128 tile-partials)/N @ W_out + b_out.
// ---------------------------------------------------------------------------
__global__ __launch_bounds__(64) void readout_kernel(
    const float* __restrict__ partial, const float* __restrict__ W_out,
    const float* __restrict__ b_out, float* __restrict__ out)
{
    const int b = blockIdx.x;
    const int hh = threadIdx.x;
    float s = 0.f;
#pragma unroll 8
    for (int c = 0; c < 128; ++c)
        s += partial[(b * 128 + c) * 64 + hh];
    float v = s * (1.0f / NN) * W_out[hh];
#pragma unroll
    for (int off = 32; off >= 1; off >>= 1) v += __shfl_xor(v, off);
    if (hh == 0) out[b] = v + b_out[0];
}

extern "C" void kernel_launch(void* const* d_in, const int* in_sizes, int n_in,
                              void* d_out, int out_size, void* d_ws, size_t ws_size,
                              hipStream_t stream)
{
    const float* x     = (const float*)d_in[0];
    const float* W_enc = (const float*)d_in[1];
    const float* b_enc = (const float*)d_in[2];
    const float* W_e1  = (const float*)d_in[3];
    const float* b_e1  = (const float*)d_in[4];
    const float* W_e2  = (const float*)d_in[5];
    const float* b_e2  = (const float*)d_in[6];
    const float* W_msg = (const float*)d_in[7];
    const float* b_msg = (const float*)d_in[8];
    const float* W_ih  = (const float*)d_in[9];
    const float* b_ih  = (const float*)d_in[10];
    const float* W_hh  = (const float*)d_in[11];
    const float* b_hh  = (const float*)d_in[12];
    const float* W_out = (const float*)d_in[13];
    const float* b_out = (const float*)d_in[14];
    float* out = (float*)d_out;

    float* ws   = (float*)d_ws;
    float* h0   = ws;
    float* h1   = h0 + BB * NN * HH;
    float* zi   = h1 + BB * NN * HH;
    float* zjT2 = zi + BB * NN * HH;        // float2[B][32][N] = B*N*H floats
    float* prt  = zjT2 + BB * NN * HH;      // 1024*64 partials
    float* adjw = prt + 1024 * 64;

    encode_kernel<<<BB * NN / 4, 256, 0, stream>>>(
        x, W_enc, b_enc, W_e1, b_e1, h0, zi, zjT2);

    adjlayer_kernel<0><<<BB * (NN / 4), 256, 0, stream>>>(
        zi, zjT2, W_e2, b_e2, adjw, h0,
        W_msg, b_msg, W_ih, b_ih, W_hh, b_hh, h1, nullptr);
    adjlayer_kernel<1><<<BB * (NN / 4), 256, 0, stream>>>(
        zi, zjT2, W_e2, b_e2, adjw, h1,
        W_msg + HH * HH, b_msg + HH,
        W_ih + HH * 3 * HH, b_ih + 3 * HH, W_hh + HH * 3 * HH, b_hh + 3 * HH,
        h0, prt);

    readout_kernel<<<BB, 64, 0, stream>>>(prt, W_out, b_out, out);
}

// Round 13
// 74.071 us; speedup vs baseline: 1.1115x; 1.1115x over previous
//
#include <hip/hip_runtime.h>
#include <math.h>

#define BB 8
#define NN 512
#define FF 32
#define HH 64
#define NEG_BIG (-1.0e30f)

__device__ __forceinline__ float lane_bcast(float v, int l) {
    return __int_as_float(__builtin_amdgcn_readlane(__float_as_int(v), l));
}

// ---------------------------------------------------------------------------
// encode: h = relu(x@W_enc+b); zi = h@W_e1[:H]+b_e1 (folded); zjT2 = second
// projection TRANSPOSED + k-pair interleaved (float2 at [b][k>>1][n]) so the
// edge loop loads 8B/lane coalesced and can use packed fp32 math.
// ---------------------------------------------------------------------------
__global__ __launch_bounds__(256) void encode_kernel(
    const float* __restrict__ x, const float* __restrict__ W_enc,
    const float* __restrict__ b_enc, const float* __restrict__ W_e1,
    const float* __restrict__ b_e1,
    float* __restrict__ h, float* __restrict__ zi, float* __restrict__ zjT2)
{
    const int t = threadIdx.x;
    const int hh = t & 63;
    const int qu = __builtin_amdgcn_readfirstlane(t >> 6);
    const int gR = blockIdx.x * 4 + qu;           // 0..B*N-1

    const float xv = x[gR * FF + (hh & 31)];      // coalesced; lanes 32+ dup
    float acc = b_enc[hh];
#pragma unroll 8
    for (int k = 0; k < FF; ++k)
        acc = fmaf(lane_bcast(xv, k), W_enc[k * HH + hh], acc);
    const float hval = fmaxf(acc, 0.f);
    h[gR * HH + hh] = hval;

    float z1 = b_e1[hh], z2 = 0.f;
#pragma unroll 8
    for (int k = 0; k < HH; ++k) {
        const float hk = lane_bcast(hval, k);
        z1 = fmaf(hk, W_e1[k * HH + hh], z1);
        z2 = fmaf(hk, W_e1[(HH + k) * HH + hh], z2);
    }
    zi[gR * HH + hh] = z1;
    const int b = gR >> 9, n = gR & (NN - 1);
    zjT2[(((size_t)b * 32 + (hh >> 1)) * NN + n) * 2 + (hh & 1)] = z2;
}

// ---------------------------------------------------------------------------
// adjlayer<MODE>: 512 blocks x 512 thr, launch_bounds(512,4) = 2 blocks/CU
// (16 waves/CU).  block = (b, 8 rows); wave w = j-slice [64w,64w+64), lane
// tj -> j = 64w+tj; later phases re-split waves by role.
// MODE 0: packed-float2 edge logits (zjT2 coalesced; zi/W_e2 s_load) +
//         softmax -> va regs, store adjw.
// MODE 1: va loaded from adjw; readout partial folded at the end.
// Phase C uses R11's (half,kh,rq) split: block weight traffic 196 KB
// (R12's all-gates-per-wave was 8x that -- the round-12 regression).
// ---------------------------------------------------------------------------
template <int MODE>
__global__ __launch_bounds__(512, 4) void adjlayer_kernel(
    const float* __restrict__ zi, const float* __restrict__ zjT2,
    const float* __restrict__ We2, const float* __restrict__ be2,
    float* __restrict__ adjw, const float* __restrict__ h_in,
    const float* __restrict__ Wmsg, const float* __restrict__ bmsg,
    const float* __restrict__ Wih, const float* __restrict__ bih,
    const float* __restrict__ Whh, const float* __restrict__ bhh,
    float* __restrict__ h_out, float* __restrict__ partial)
{
    const int b  = blockIdx.x >> 6;
    const int i0 = (blockIdx.x & 63) << 3;        // 8 rows
    const int t  = threadIdx.x;
    const int tj = t & 63;
    const int w  = __builtin_amdgcn_readfirstlane(t >> 6);   // 0..7
    const int gR0 = b * NN + i0;
    const int j   = 64 * w + tj;

    __shared__ float smem[6336];                  // union RED(4224)/GP(6336)
    __shared__ float mml[8][66];
    __shared__ float hol[8][66];
    __shared__ float redm[8][8], reds[8][8];
#define RED(p, r, c)        smem[(((p) * 8) + (r)) * 66 + (c)]
#define GP(h2, k2, r, g, c) smem[(((((h2) * 2 + (k2)) * 8 + (r)) * 3 + (g)) * 66) + (c)]

    hol[w][tj] = h_in[(size_t)(gR0 + w) * HH + tj];

    //=== adjacency slice in registers: va[r] = adj[i0+r][j] =================
    float va[8];
    if (MODE == 0) {
        const float2* zi2 = (const float2*)(zi + (size_t)gR0 * HH);  // s_load
        const float2* we2 = (const float2*)We2;                      // s_load
        const float2* zt2 = (const float2*)zjT2 + (size_t)b * 32 * NN + j;

        float2 a2[8];
#pragma unroll
        for (int r = 0; r < 8; ++r) a2[r] = make_float2(0.f, 0.f);
#pragma unroll 8
        for (int k2 = 0; k2 < 32; ++k2) {
            const float2 z = zt2[(size_t)k2 * NN];     // 8B coalesced
            const float2 wk = we2[k2];                 // s_load
#pragma unroll
            for (int r = 0; r < 8; ++r) {
                const float2 zv = zi2[r * 32 + k2];    // s_load
                a2[r].x = fmaf(fmaxf(zv.x + z.x, 0.f), wk.x, a2[r].x);
                a2[r].y = fmaf(fmaxf(zv.y + z.y, 0.f), wk.y, a2[r].y);
            }
        }
        const float bias2 = be2[0];
        float acc[8];
#pragma unroll
        for (int r = 0; r < 8; ++r) {
            acc[r] = a2[r].x + a2[r].y + bias2;
            if (j == i0 + r) acc[r] = NEG_BIG;         // diag mask
        }

        // softmax over j: in-wave shfl + cross-wave (8 slices) LDS reduce
#pragma unroll
        for (int r = 0; r < 8; ++r) {
            float m = acc[r];
#pragma unroll
            for (int off = 32; off >= 1; off >>= 1)
                m = fmaxf(m, __shfl_xor(m, off));
            if (tj == 0) redm[w][r] = m;
        }
        __syncthreads();
        float M[8];
#pragma unroll
        for (int r = 0; r < 8; ++r) {
            float m = redm[0][r];
#pragma unroll
            for (int p = 1; p < 8; ++p) m = fmaxf(m, redm[p][r]);
            M[r] = m;
        }
#pragma unroll
        for (int r = 0; r < 8; ++r) {
            va[r] = __expf(acc[r] - M[r]);
            float s = va[r];
#pragma unroll
            for (int off = 32; off >= 1; off >>= 1) s += __shfl_xor(s, off);
            if (tj == 0) reds[w][r] = s;
        }
        __syncthreads();
#pragma unroll
        for (int r = 0; r < 8; ++r) {
            float s = reds[0][r];
#pragma unroll
            for (int p = 1; p < 8; ++p) s += reds[p][r];
            va[r] *= 1.0f / s;
            adjw[(size_t)(gR0 + r) * NN + j] = va[r];
        }
    } else {
#pragma unroll
        for (int r = 0; r < 8; ++r)
            va[r] = adjw[(size_t)(gR0 + r) * NN + j];
    }

    //=== phase A: m partials (wave w: its 64-j slice, all 8 rows) ===========
    {
        const float* hq = h_in + ((size_t)b * NN + 64 * w) * HH + tj;
        float mac[8] = {0.f, 0.f, 0.f, 0.f, 0.f, 0.f, 0.f, 0.f};
#pragma unroll 4
        for (int jj = 0; jj < 64; ++jj) {
            const float hv = hq[(size_t)jj * HH];
#pragma unroll
            for (int r = 0; r < 8; ++r)
                mac[r] = fmaf(lane_bcast(va[r], jj), hv, mac[r]);
        }
#pragma unroll
        for (int r = 0; r < 8; ++r) RED(w, r, tj) = mac[r];
    }
    __syncthreads();

    //=== phase B: wave w = row w: m reduce + mm GEMM ========================
    {
        float m = RED(0, w, tj);
#pragma unroll
        for (int p = 1; p < 8; ++p) m += RED(p, w, tj);
        float mmv = bmsg[tj];
#pragma unroll 8
        for (int k = 0; k < HH; ++k)
            mmv = fmaf(lane_bcast(m, k), Wmsg[k * HH + tj], mmv);
        mml[w][tj] = fmaxf(mmv, 0.f);
    }
    __syncthreads();   // mml ready; RED dead -> GP overlay legal

    //=== phase C: wave = (half, kh, rq): 3 gates x 4 rows x 32 k ============
    {
        const int half = w >> 2, kh = (w >> 1) & 1, rq = w & 1;
        const float* Wg = half ? Whh : Wih;
        const float* bg = half ? bhh : bih;
        float sreg[4];
#pragma unroll
        for (int r = 0; r < 4; ++r)
            sreg[r] = half ? hol[rq * 4 + r][tj] : mml[rq * 4 + r][tj];
        float g0[4], g1[4], g2[4];
#pragma unroll
        for (int r = 0; r < 4; ++r) {
            g0[r] = kh ? 0.f : bg[tj];
            g1[r] = kh ? 0.f : bg[64 + tj];
            g2[r] = kh ? 0.f : bg[128 + tj];
        }
        const int k0 = kh * 32;
#pragma unroll 4
        for (int kk = 0; kk < 32; ++kk) {
            const float* wk = Wg + (size_t)(k0 + kk) * 192;
            const float w0 = wk[tj], w1 = wk[64 + tj], w2 = wk[128 + tj];
#pragma unroll
            for (int r = 0; r < 4; ++r) {
                const float s = lane_bcast(sreg[r], k0 + kk);
                g0[r] = fmaf(s, w0, g0[r]);
                g1[r] = fmaf(s, w1, g1[r]);
                g2[r] = fmaf(s, w2, g2[r]);
            }
        }
#pragma unroll
        for (int r = 0; r < 4; ++r) {
            GP(half, kh, rq * 4 + r, 0, tj) = g0[r];
            GP(half, kh, rq * 4 + r, 1, tj) = g1[r];
            GP(half, kh, rq * 4 + r, 2, tj) = g2[r];
        }
    }
    __syncthreads();

    //=== finalize: wave w = row w ===========================================
    float hnew;
    {
        const float ir  = GP(0, 0, w, 0, tj) + GP(0, 1, w, 0, tj);
        const float iz  = GP(0, 0, w, 1, tj) + GP(0, 1, w, 1, tj);
        const float inn = GP(0, 0, w, 2, tj) + GP(0, 1, w, 2, tj);
        const float hr  = GP(1, 0, w, 0, tj) + GP(1, 1, w, 0, tj);
        const float hz  = GP(1, 0, w, 1, tj) + GP(1, 1, w, 1, tj);
        const float hn  = GP(1, 0, w, 2, tj) + GP(1, 1, w, 2, tj);
        const float rg = 1.f / (1.f + __expf(-(ir + hr)));
        const float zg = 1.f / (1.f + __expf(-(iz + hz)));
        const float ng = tanhf(inn + rg * hn);
        hnew = (1.f - zg) * ng + zg * hol[w][tj];
        h_out[(size_t)(gR0 + w) * HH + tj] = hnew;
    }

    if (MODE == 1) {   // readout partial: block sum of its 8 rows
        __syncthreads();                  // mml reads in C all done
        mml[w][tj] = hnew;
        __syncthreads();
        if (w == 0) {
            float s = 0.f;
#pragma unroll
            for (int r = 0; r < 8; ++r) s += mml[r][tj];
            partial[blockIdx.x * 64 + tj] = s;
        }
    }
#undef RED
#undef GP
}

// ---------------------------------------------------------------------------
// readout: out[b] = (sum of 64 tile-partials)/N @ W_out + b_out.
// ---------------------------------------------------------------------------
__global__ __launch_bounds__(64) void readout_kernel(
    const float* __restrict__ partial, const float* __restrict__ W_out,
    const float* __restrict__ b_out, float* __restrict__ out)
{
    const int b = blockIdx.x;
    const int hh = threadIdx.x;
    float s = 0.f;
#pragma unroll 8
    for (int c = 0; c < 64; ++c)
        s += partial[(b * 64 + c) * 64 + hh];
    float v = s * (1.0f / NN) * W_out[hh];
#pragma unroll
    for (int off = 32; off >= 1; off >>= 1) v += __shfl_xor(v, off);
    if (hh == 0) out[b] = v + b_out[0];
}

extern "C" void kernel_launch(void* const* d_in, const int* in_sizes, int n_in,
                              void* d_out, int out_size, void* d_ws, size_t ws_size,
                              hipStream_t stream)
{
    const float* x     = (const float*)d_in[0];
    const float* W_enc = (const float*)d_in[1];
    const float* b_enc = (const float*)d_in[2];
    const float* W_e1  = (const float*)d_in[3];
    const float* b_e1  = (const float*)d_in[4];
    const float* W_e2  = (const float*)d_in[5];
    const float* b_e2  = (const float*)d_in[6];
    const float* W_msg = (const float*)d_in[7];
    const float* b_msg = (const float*)d_in[8];
    const float* W_ih  = (const float*)d_in[9];
    const float* b_ih  = (const float*)d_in[10];
    const float* W_hh  = (const float*)d_in[11];
    const float* b_hh  = (const float*)d_in[12];
    const float* W_out = (const float*)d_in[13];
    const float* b_out = (const float*)d_in[14];
    float* out = (float*)d_out;

    float* ws   = (float*)d_ws;
    float* h0   = ws;
    float* h1   = h0 + BB * NN * HH;
    float* zi   = h1 + BB * NN * HH;
    float* zjT2 = zi + BB * NN * HH;        // float2[B][32][N]
    float* prt  = zjT2 + BB * NN * HH;      // 512*64 partials
    float* adjw = prt + 512 * 64;

    encode_kernel<<<BB * NN / 4, 256, 0, stream>>>(
        x, W_enc, b_enc, W_e1, b_e1, h0, zi, zjT2);

    adjlayer_kernel<0><<<BB * (NN / 8), 512, 0, stream>>>(
        zi, zjT2, W_e2, b_e2, adjw, h0,
        W_msg, b_msg, W_ih, b_ih, W_hh, b_hh, h1, nullptr);
    adjlayer_kernel<1><<<BB * (NN / 8), 512, 0, stream>>>(
        zi, zjT2, W_e2, b_e2, adjw, h1,
        W_msg + HH * HH, b_msg + HH,
        W_ih + HH * 3 * HH, b_ih + 3 * HH, W_hh + HH * 3 * HH, b_hh + 3 * HH,
        h0, prt);

    readout_kernel<<<BB, 64, 0, stream>>>(prt, W_out, b_out, out);
}

// Round 14
// 72.785 us; speedup vs baseline: 1.1311x; 1.0177x over previous
//
#include <hip/hip_runtime.h>
#include <math.h>

#define BB 8
#define NN 512
#define FF 32
#define HH 64
#define NEG_BIG (-1.0e30f)

__device__ __forceinline__ float lane_bcast(float v, int l) {
    return __int_as_float(__builtin_amdgcn_readlane(__float_as_int(v), l));
}

// ---------------------------------------------------------------------------
// encode: h = relu(x@W_enc+b); zi = h@W_e1[:H]+b_e1 (folded); zjT2 = second
// projection TRANSPOSED + k-pair interleaved (float2 at [b][k>>1][n]).
// ---------------------------------------------------------------------------
__global__ __launch_bounds__(256) void encode_kernel(
    const float* __restrict__ x, const float* __restrict__ W_enc,
    const float* __restrict__ b_enc, const float* __restrict__ W_e1,
    const float* __restrict__ b_e1,
    float* __restrict__ h, float* __restrict__ zi, float* __restrict__ zjT2)
{
    const int t = threadIdx.x;
    const int hh = t & 63;
    const int qu = __builtin_amdgcn_readfirstlane(t >> 6);
    const int gR = blockIdx.x * 4 + qu;           // 0..B*N-1

    const float xv = x[gR * FF + (hh & 31)];      // coalesced; lanes 32+ dup
    float acc = b_enc[hh];
#pragma unroll 8
    for (int k = 0; k < FF; ++k)
        acc = fmaf(lane_bcast(xv, k), W_enc[k * HH + hh], acc);
    const float hval = fmaxf(acc, 0.f);
    h[gR * HH + hh] = hval;

    float z1 = b_e1[hh], z2 = 0.f;
#pragma unroll 8
    for (int k = 0; k < HH; ++k) {
        const float hk = lane_bcast(hval, k);
        z1 = fmaf(hk, W_e1[k * HH + hh], z1);
        z2 = fmaf(hk, W_e1[(HH + k) * HH + hh], z2);
    }
    zi[gR * HH + hh] = z1;
    const int b = gR >> 9, n = gR & (NN - 1);
    zjT2[(((size_t)b * 32 + (hh >> 1)) * NN + n) * 2 + (hh & 1)] = z2;
}

// ---------------------------------------------------------------------------
// adjlayer<MODE>: 1024 blocks x 512 thr, __launch_bounds__(512,8) ->
// 4 blocks/CU x 8 waves = 32 waves/CU (HW max; R11-R13 all ran 16).
// block = (b, 4 rows); wave w = j-slice [64w,64w+64).
// MODE 0: packed-float2 edge logits + softmax -> va regs, store adjw.
// MODE 1: phase A reads adj via wave-uniform s_loads (prev-kernel data, so
//         scalar cache is safe) -- no readlane in the A loop.
// Phase B: waves 0-3 (row w).  Phase C: (half,kh,rq) split, 2 rows each.
// ---------------------------------------------------------------------------
template <int MODE>
__global__ __launch_bounds__(512, 8) void adjlayer_kernel(
    const float* __restrict__ zi, const float* __restrict__ zjT2,
    const float* __restrict__ We2, const float* __restrict__ be2,
    float* __restrict__ adjw, const float* __restrict__ adjr,
    const float* __restrict__ h_in,
    const float* __restrict__ Wmsg, const float* __restrict__ bmsg,
    const float* __restrict__ Wih, const float* __restrict__ bih,
    const float* __restrict__ Whh, const float* __restrict__ bhh,
    float* __restrict__ h_out, float* __restrict__ partial)
{
    const int b  = blockIdx.x >> 7;               // 1024 = 8 b x 128 tiles
    const int i0 = (blockIdx.x & 127) << 2;       // 4 rows
    const int t  = threadIdx.x;
    const int tj = t & 63;
    const int w  = __builtin_amdgcn_readfirstlane(t >> 6);   // 0..7
    const int gR0 = b * NN + i0;
    const int j   = 64 * w + tj;

    __shared__ float smem[3168];                  // union RED[8][4][66]/GP[2][2][4][3][66]
    __shared__ float mml[4][66];
    __shared__ float hol[4][66];
    __shared__ float redm[8][4], reds[8][4];
#define RED(p, r, c)        smem[(((p) * 4) + (r)) * 66 + (c)]
#define GP(h2, k2, r, g, c) smem[(((((h2) * 2 + (k2)) * 4 + (r)) * 3 + (g)) * 66) + (c)]

    if (w < 4) hol[w][tj] = h_in[(size_t)(gR0 + w) * HH + tj];

    //=== adjacency slice: va[r] = adj[i0+r][j] (MODE 0 only) ================
    float va[4];
    if (MODE == 0) {
        const float2* zi2 = (const float2*)(zi + (size_t)gR0 * HH);  // s_load
        const float2* we2 = (const float2*)We2;                      // s_load
        const float2* zt2 = (const float2*)zjT2 + (size_t)b * 32 * NN + j;

        float2 a2[4];
#pragma unroll
        for (int r = 0; r < 4; ++r) a2[r] = make_float2(0.f, 0.f);
#pragma unroll 8
        for (int k2 = 0; k2 < 32; ++k2) {
            const float2 z = zt2[(size_t)k2 * NN];     // 8B coalesced
            const float2 wk = we2[k2];                 // s_load
#pragma unroll
            for (int r = 0; r < 4; ++r) {
                const float2 zv = zi2[r * 32 + k2];    // s_load
                a2[r].x = fmaf(fmaxf(zv.x + z.x, 0.f), wk.x, a2[r].x);
                a2[r].y = fmaf(fmaxf(zv.y + z.y, 0.f), wk.y, a2[r].y);
            }
        }
        const float bias2 = be2[0];
        float acc[4];
#pragma unroll
        for (int r = 0; r < 4; ++r) {
            acc[r] = a2[r].x + a2[r].y + bias2;
            if (j == i0 + r) acc[r] = NEG_BIG;         // diag mask
        }

        // softmax over j: in-wave shfl + cross-wave (8 slices) LDS reduce
#pragma unroll
        for (int r = 0; r < 4; ++r) {
            float m = acc[r];
#pragma unroll
            for (int off = 32; off >= 1; off >>= 1)
                m = fmaxf(m, __shfl_xor(m, off));
            if (tj == 0) redm[w][r] = m;
        }
        __syncthreads();
        float M[4];
#pragma unroll
        for (int r = 0; r < 4; ++r) {
            float m = redm[0][r];
#pragma unroll
            for (int p = 1; p < 8; ++p) m = fmaxf(m, redm[p][r]);
            M[r] = m;
        }
#pragma unroll
        for (int r = 0; r < 4; ++r) {
            va[r] = __expf(acc[r] - M[r]);
            float s = va[r];
#pragma unroll
            for (int off = 32; off >= 1; off >>= 1) s += __shfl_xor(s, off);
            if (tj == 0) reds[w][r] = s;
        }
        __syncthreads();
#pragma unroll
        for (int r = 0; r < 4; ++r) {
            float s = reds[0][r];
#pragma unroll
            for (int p = 1; p < 8; ++p) s += reds[p][r];
            va[r] *= 1.0f / s;
            adjw[(size_t)(gR0 + r) * NN + j] = va[r];
        }
    }

    //=== phase A: m partials (wave w: its 64-j slice, all 4 rows) ===========
    {
        const float* hq = h_in + ((size_t)b * NN + 64 * w) * HH + tj;
        float mac[4] = {0.f, 0.f, 0.f, 0.f};
        if (MODE == 0) {
#pragma unroll 4
            for (int jj = 0; jj < 64; ++jj) {
                const float hv = hq[(size_t)jj * HH];
#pragma unroll
                for (int r = 0; r < 4; ++r)
                    mac[r] = fmaf(lane_bcast(va[r], jj), hv, mac[r]);
            }
        } else {
            // adj via wave-uniform s_loads (SMEM pipe, zero VALU)
            const float* a0 = adjr + (size_t)(gR0 + 0) * NN + 64 * w;
            const float* a1 = adjr + (size_t)(gR0 + 1) * NN + 64 * w;
            const float* a2 = adjr + (size_t)(gR0 + 2) * NN + 64 * w;
            const float* a3 = adjr + (size_t)(gR0 + 3) * NN + 64 * w;
#pragma unroll 8
            for (int jj = 0; jj < 64; ++jj) {
                const float hv = hq[(size_t)jj * HH];
                mac[0] = fmaf(a0[jj], hv, mac[0]);
                mac[1] = fmaf(a1[jj], hv, mac[1]);
                mac[2] = fmaf(a2[jj], hv, mac[2]);
                mac[3] = fmaf(a3[jj], hv, mac[3]);
            }
        }
#pragma unroll
        for (int r = 0; r < 4; ++r) RED(w, r, tj) = mac[r];
    }
    __syncthreads();

    //=== phase B: waves 0-3, wave w = row w: m reduce + mm GEMM =============
    if (w < 4) {
        float m = RED(0, w, tj);
#pragma unroll
        for (int p = 1; p < 8; ++p) m += RED(p, w, tj);
        float mmv = bmsg[tj];
#pragma unroll 8
        for (int k = 0; k < HH; ++k)
            mmv = fmaf(lane_bcast(m, k), Wmsg[k * HH + tj], mmv);
        mml[w][tj] = fmaxf(mmv, 0.f);
    }
    __syncthreads();   // mml ready; RED dead -> GP overlay legal

    //=== phase C: wave = (half, kh, rq): 3 gates x 2 rows x 32 k ============
    {
        const int half = w >> 2, kh = (w >> 1) & 1, rq = w & 1;
        const float* Wg = half ? Whh : Wih;
        const float* bg = half ? bhh : bih;
        float sreg[2];
#pragma unroll
        for (int r = 0; r < 2; ++r)
            sreg[r] = half ? hol[rq * 2 + r][tj] : mml[rq * 2 + r][tj];
        float g0[2], g1[2], g2[2];
#pragma unroll
        for (int r = 0; r < 2; ++r) {
            g0[r] = kh ? 0.f : bg[tj];
            g1[r] = kh ? 0.f : bg[64 + tj];
            g2[r] = kh ? 0.f : bg[128 + tj];
        }
        const int k0 = kh * 32;
#pragma unroll 4
        for (int kk = 0; kk < 32; ++kk) {
            const float* wk = Wg + (size_t)(k0 + kk) * 192;
            const float w0 = wk[tj], w1 = wk[64 + tj], w2 = wk[128 + tj];
#pragma unroll
            for (int r = 0; r < 2; ++r) {
                const float s = lane_bcast(sreg[r], k0 + kk);
                g0[r] = fmaf(s, w0, g0[r]);
                g1[r] = fmaf(s, w1, g1[r]);
                g2[r] = fmaf(s, w2, g2[r]);
            }
        }
#pragma unroll
        for (int r = 0; r < 2; ++r) {
            GP(half, kh, rq * 2 + r, 0, tj) = g0[r];
            GP(half, kh, rq * 2 + r, 1, tj) = g1[r];
            GP(half, kh, rq * 2 + r, 2, tj) = g2[r];
        }
    }
    __syncthreads();

    //=== finalize: waves 0-3, wave w = row w ================================
    float hnew = 0.f;
    if (w < 4) {
        const float ir  = GP(0, 0, w, 0, tj) + GP(0, 1, w, 0, tj);
        const float iz  = GP(0, 0, w, 1, tj) + GP(0, 1, w, 1, tj);
        const float inn = GP(0, 0, w, 2, tj) + GP(0, 1, w, 2, tj);
        const float hr  = GP(1, 0, w, 0, tj) + GP(1, 1, w, 0, tj);
        const float hz  = GP(1, 0, w, 1, tj) + GP(1, 1, w, 1, tj);
        const float hn  = GP(1, 0, w, 2, tj) + GP(1, 1, w, 2, tj);
        const float rg = 1.f / (1.f + __expf(-(ir + hr)));
        const float zg = 1.f / (1.f + __expf(-(iz + hz)));
        const float ng = tanhf(inn + rg * hn);
        hnew = (1.f - zg) * ng + zg * hol[w][tj];
        h_out[(size_t)(gR0 + w) * HH + tj] = hnew;
    }

    if (MODE == 1) {   // readout partial: block sum of its 4 rows
        __syncthreads();                  // phase C mml reads complete
        if (w < 4) mml[w][tj] = hnew;
        __syncthreads();
        if (w == 0) {
            partial[blockIdx.x * 64 + tj] =
                mml[0][tj] + mml[1][tj] + mml[2][tj] + mml[3][tj];
        }
    }
#undef RED
#undef GP
}

// ---------------------------------------------------------------------------
// readout: out[b] = (sum of 128 tile-partials)/N @ W_out + b_out.
// ---------------------------------------------------------------------------
__global__ __launch_bounds__(64) void readout_kernel(
    const float* __restrict__ partial, const float* __restrict__ W_out,
    const float* __restrict__ b_out, float* __restrict__ out)
{
    const int b = blockIdx.x;
    const int hh = threadIdx.x;
    float s = 0.f;
#pragma unroll 8
    for (int c = 0; c < 128; ++c)
        s += partial[(b * 128 + c) * 64 + hh];
    float v = s * (1.0f / NN) * W_out[hh];
#pragma unroll
    for (int off = 32; off >= 1; off >>= 1) v += __shfl_xor(v, off);
    if (hh == 0) out[b] = v + b_out[0];
}

extern "C" void kernel_launch(void* const* d_in, const int* in_sizes, int n_in,
                              void* d_out, int out_size, void* d_ws, size_t ws_size,
                              hipStream_t stream)
{
    const float* x     = (const float*)d_in[0];
    const float* W_enc = (const float*)d_in[1];
    const float* b_enc = (const float*)d_in[2];
    const float* W_e1  = (const float*)d_in[3];
    const float* b_e1  = (const float*)d_in[4];
    const float* W_e2  = (const float*)d_in[5];
    const float* b_e2  = (const float*)d_in[6];
    const float* W_msg = (const float*)d_in[7];
    const float* b_msg = (const float*)d_in[8];
    const float* W_ih  = (const float*)d_in[9];
    const float* b_ih  = (const float*)d_in[10];
    const float* W_hh  = (const float*)d_in[11];
    const float* b_hh  = (const float*)d_in[12];
    const float* W_out = (const float*)d_in[13];
    const float* b_out = (const float*)d_in[14];
    float* out = (float*)d_out;

    float* ws   = (float*)d_ws;
    float* h0   = ws;
    float* h1   = h0 + BB * NN * HH;
    float* zi   = h1 + BB * NN * HH;
    float* zjT2 = zi + BB * NN * HH;        // float2[B][32][N]
    float* prt  = zjT2 + BB * NN * HH;      // 1024*64 partials
    float* adjw = prt + 1024 * 64;

    encode_kernel<<<BB * NN / 4, 256, 0, stream>>>(
        x, W_enc, b_enc, W_e1, b_e1, h0, zi, zjT2);

    adjlayer_kernel<0><<<BB * (NN / 4), 512, 0, stream>>>(
        zi, zjT2, W_e2, b_e2, adjw, adjw, h0,
        W_msg, b_msg, W_ih, b_ih, W_hh, b_hh, h1, nullptr);
    adjlayer_kernel<1><<<BB * (NN / 4), 512, 0, stream>>>(
        zi, zjT2, W_e2, b_e2, adjw, adjw, h1,
        W_msg + HH * HH, b_msg + HH,
        W_ih + HH * 3 * HH, b_ih + 3 * HH, W_hh + HH * 3 * HH, b_hh + 3 * HH,
        h0, prt);

    readout_kernel<<<BB, 64, 0, stream>>>(prt, W_out, b_out, out);
}

// Round 15
// 72.186 us; speedup vs baseline: 1.1405x; 1.0083x over previous
//
#include <hip/hip_runtime.h>
#include <math.h>

#define BB 8
#define NN 512
#define FF 32
#define HH 64
#define NEG_BIG (-1.0e30f)

__device__ __forceinline__ float lane_bcast(float v, int l) {
    return __int_as_float(__builtin_amdgcn_readlane(__float_as_int(v), l));
}

// ---------------------------------------------------------------------------
// encode: h = relu(x@W_enc+b); zi = h@W_e1[:H]+b_e1 (folded); zjT2 = second
// projection TRANSPOSED + k-pair interleaved (float2 at [b][k>>1][n]).
// ---------------------------------------------------------------------------
__global__ __launch_bounds__(256) void encode_kernel(
    const float* __restrict__ x, const float* __restrict__ W_enc,
    const float* __restrict__ b_enc, const float* __restrict__ W_e1,
    const float* __restrict__ b_e1,
    float* __restrict__ h, float* __restrict__ zi, float* __restrict__ zjT2)
{
    const int t = threadIdx.x;
    const int hh = t & 63;
    const int qu = __builtin_amdgcn_readfirstlane(t >> 6);
    const int gR = blockIdx.x * 4 + qu;           // 0..B*N-1

    const float xv = x[gR * FF + (hh & 31)];      // coalesced; lanes 32+ dup
    float acc = b_enc[hh];
#pragma unroll 8
    for (int k = 0; k < FF; ++k)
        acc = fmaf(lane_bcast(xv, k), W_enc[k * HH + hh], acc);
    const float hval = fmaxf(acc, 0.f);
    h[gR * HH + hh] = hval;

    float z1 = b_e1[hh], z2 = 0.f;
#pragma unroll 8
    for (int k = 0; k < HH; ++k) {
        const float hk = lane_bcast(hval, k);
        z1 = fmaf(hk, W_e1[k * HH + hh], z1);
        z2 = fmaf(hk, W_e1[(HH + k) * HH + hh], z2);
    }
    zi[gR * HH + hh] = z1;
    const int b = gR >> 9, n = gR & (NN - 1);
    zjT2[(((size_t)b * 32 + (hh >> 1)) * NN + n) * 2 + (hh & 1)] = z2;
}

// ---------------------------------------------------------------------------
// adj (STANDALONE -- R10-R14 fusion measurably doubled its cost via VGPR/
// phase pressure; standalone history: ~10-12us): 1024 blocks x 512 thr,
// (512,8) = 32 waves/CU.  block = (b, 4 rows); wave w = j-slice
// [64w, 64w+64), lane tj -> j = 64w+tj.
// Edge loop: zjT2 8B/lane coalesced; zi & W_e2 block-uniform s_loads.
// Softmax cross-wave via tiny LDS reduce.  Also inits out[b] = b_out
// (stream order guarantees this precedes layer-2's atomic adds).
// ---------------------------------------------------------------------------
__global__ __launch_bounds__(512, 8) void adj_kernel(
    const float* __restrict__ zi, const float* __restrict__ zjT2,
    const float* __restrict__ We2, const float* __restrict__ be2,
    const float* __restrict__ b_out,
    float* __restrict__ adjw, float* __restrict__ out)
{
    const int b  = blockIdx.x >> 7;
    const int i0 = (blockIdx.x & 127) << 2;
    const int t  = threadIdx.x;
    const int tj = t & 63;
    const int w  = __builtin_amdgcn_readfirstlane(t >> 6);   // 0..7
    const int gR0 = b * NN + i0;
    const int j   = 64 * w + tj;

    __shared__ float redm[8][4], reds[8][4];

    if (blockIdx.x < BB && t == 0) out[blockIdx.x] = b_out[0];  // init for atomics

    const float2* zi2 = (const float2*)(zi + (size_t)gR0 * HH);  // s_load
    const float2* we2 = (const float2*)We2;                      // s_load
    const float2* zt2 = (const float2*)zjT2 + (size_t)b * 32 * NN + j;

    float2 a2[4];
#pragma unroll
    for (int r = 0; r < 4; ++r) a2[r] = make_float2(0.f, 0.f);
#pragma unroll 8
    for (int k2 = 0; k2 < 32; ++k2) {
        const float2 z = zt2[(size_t)k2 * NN];     // 8B coalesced
        const float2 wk = we2[k2];                 // s_load
#pragma unroll
        for (int r = 0; r < 4; ++r) {
            const float2 zv = zi2[r * 32 + k2];    // s_load
            a2[r].x = fmaf(fmaxf(zv.x + z.x, 0.f), wk.x, a2[r].x);
            a2[r].y = fmaf(fmaxf(zv.y + z.y, 0.f), wk.y, a2[r].y);
        }
    }
    const float bias2 = be2[0];
    float acc[4];
#pragma unroll
    for (int r = 0; r < 4; ++r) {
        acc[r] = a2[r].x + a2[r].y + bias2;
        if (j == i0 + r) acc[r] = NEG_BIG;         // diag mask
    }

    // softmax over j: in-wave shfl + cross-wave (8 slices) LDS reduce
#pragma unroll
    for (int r = 0; r < 4; ++r) {
        float m = acc[r];
#pragma unroll
        for (int off = 32; off >= 1; off >>= 1)
            m = fmaxf(m, __shfl_xor(m, off));
        if (tj == 0) redm[w][r] = m;
    }
    __syncthreads();
    float M[4];
#pragma unroll
    for (int r = 0; r < 4; ++r) {
        float m = redm[0][r];
#pragma unroll
        for (int p = 1; p < 8; ++p) m = fmaxf(m, redm[p][r]);
        M[r] = m;
    }
    float e[4];
#pragma unroll
    for (int r = 0; r < 4; ++r) {
        e[r] = __expf(acc[r] - M[r]);
        float s = e[r];
#pragma unroll
        for (int off = 32; off >= 1; off >>= 1) s += __shfl_xor(s, off);
        if (tj == 0) reds[w][r] = s;
    }
    __syncthreads();
#pragma unroll
    for (int r = 0; r < 4; ++r) {
        float s = reds[0][r];
#pragma unroll
        for (int p = 1; p < 8; ++p) s += reds[p][r];
        adjw[(size_t)(gR0 + r) * NN + j] = e[r] * (1.0f / s);
    }
}

// ---------------------------------------------------------------------------
// layer<LAST>: 1024 blocks x 512 thr, (512,8) = 32 waves/CU.
// block = (b, 4 rows); wave w = j-slice for phase A.
// Phase A: adj rows via wave-uniform s_loads (zero VALU), h coalesced.
// Phase B: waves 0-3 = row w: m reduce + mm GEMM (readlane).
// Phase C: (half,kh,rq) split -- block weight traffic minimal (R12 lesson).
// LAST: fold readout -- block dots its 4-row sum with W_out/N and does ONE
// scalar atomicAdd into out[b] (order noise << 3.7e-4 threshold; out is
// re-initialized by adj_kernel every call, so graph replay is safe).
// ---------------------------------------------------------------------------
template <int LAST>
__global__ __launch_bounds__(512, 8) void layer_kernel(
    const float* __restrict__ adjr, const float* __restrict__ h_in,
    const float* __restrict__ Wmsg, const float* __restrict__ bmsg,
    const float* __restrict__ Wih, const float* __restrict__ bih,
    const float* __restrict__ Whh, const float* __restrict__ bhh,
    const float* __restrict__ Wout,
    float* __restrict__ h_out, float* __restrict__ out)
{
    const int b  = blockIdx.x >> 7;
    const int i0 = (blockIdx.x & 127) << 2;
    const int t  = threadIdx.x;
    const int tj = t & 63;
    const int w  = __builtin_amdgcn_readfirstlane(t >> 6);   // 0..7
    const int gR0 = b * NN + i0;

    __shared__ float smem[3168];                  // union RED[8][4][66]/GP[2][2][4][3][66]
    __shared__ float mml[4][66];
    __shared__ float hol[4][66];
#define RED(p, r, c)        smem[(((p) * 4) + (r)) * 66 + (c)]
#define GP(h2, k2, r, g, c) smem[(((((h2) * 2 + (k2)) * 4 + (r)) * 3 + (g)) * 66) + (c)]

    if (w < 4) hol[w][tj] = h_in[(size_t)(gR0 + w) * HH + tj];

    //=== phase A: m partials (adj via s_load, h coalesced) ==================
    {
        const float* hq = h_in + ((size_t)b * NN + 64 * w) * HH + tj;
        const float* a0 = adjr + (size_t)(gR0 + 0) * NN + 64 * w;
        const float* a1 = adjr + (size_t)(gR0 + 1) * NN + 64 * w;
        const float* a2 = adjr + (size_t)(gR0 + 2) * NN + 64 * w;
        const float* a3 = adjr + (size_t)(gR0 + 3) * NN + 64 * w;
        float mac[4] = {0.f, 0.f, 0.f, 0.f};
#pragma unroll 8
        for (int jj = 0; jj < 64; ++jj) {
            const float hv = hq[(size_t)jj * HH];
            mac[0] = fmaf(a0[jj], hv, mac[0]);
            mac[1] = fmaf(a1[jj], hv, mac[1]);
            mac[2] = fmaf(a2[jj], hv, mac[2]);
            mac[3] = fmaf(a3[jj], hv, mac[3]);
        }
#pragma unroll
        for (int r = 0; r < 4; ++r) RED(w, r, tj) = mac[r];
    }
    __syncthreads();

    //=== phase B: waves 0-3, wave w = row w: m reduce + mm GEMM =============
    if (w < 4) {
        float m = RED(0, w, tj);
#pragma unroll
        for (int p = 1; p < 8; ++p) m += RED(p, w, tj);
        float mmv = bmsg[tj];
#pragma unroll 8
        for (int k = 0; k < HH; ++k)
            mmv = fmaf(lane_bcast(m, k), Wmsg[k * HH + tj], mmv);
        mml[w][tj] = fmaxf(mmv, 0.f);
    }
    __syncthreads();   // mml ready; RED dead -> GP overlay legal

    //=== phase C: wave = (half, kh, rq): 3 gates x 2 rows x 32 k ============
    {
        const int half = w >> 2, kh = (w >> 1) & 1, rq = w & 1;
        const float* Wg = half ? Whh : Wih;
        const float* bg = half ? bhh : bih;
        float sreg[2];
#pragma unroll
        for (int r = 0; r < 2; ++r)
            sreg[r] = half ? hol[rq * 2 + r][tj] : mml[rq * 2 + r][tj];
        float g0[2], g1[2], g2[2];
#pragma unroll
        for (int r = 0; r < 2; ++r) {
            g0[r] = kh ? 0.f : bg[tj];
            g1[r] = kh ? 0.f : bg[64 + tj];
            g2[r] = kh ? 0.f : bg[128 + tj];
        }
        const int k0 = kh * 32;
#pragma unroll 4
        for (int kk = 0; kk < 32; ++kk) {
            const float* wk = Wg + (size_t)(k0 + kk) * 192;
            const float w0 = wk[tj], w1 = wk[64 + tj], w2 = wk[128 + tj];
#pragma unroll
            for (int r = 0; r < 2; ++r) {
                const float s = lane_bcast(sreg[r], k0 + kk);
                g0[r] = fmaf(s, w0, g0[r]);
                g1[r] = fmaf(s, w1, g1[r]);
                g2[r] = fmaf(s, w2, g2[r]);
            }
        }
#pragma unroll
        for (int r = 0; r < 2; ++r) {
            GP(half, kh, rq * 2 + r, 0, tj) = g0[r];
            GP(half, kh, rq * 2 + r, 1, tj) = g1[r];
            GP(half, kh, rq * 2 + r, 2, tj) = g2[r];
        }
    }
    __syncthreads();

    //=== finalize: waves 0-3, wave w = row w ================================
    float hnew = 0.f;
    if (w < 4) {
        const float ir  = GP(0, 0, w, 0, tj) + GP(0, 1, w, 0, tj);
        const float iz  = GP(0, 0, w, 1, tj) + GP(0, 1, w, 1, tj);
        const float inn = GP(0, 0, w, 2, tj) + GP(0, 1, w, 2, tj);
        const float hr  = GP(1, 0, w, 0, tj) + GP(1, 1, w, 0, tj);
        const float hz  = GP(1, 0, w, 1, tj) + GP(1, 1, w, 1, tj);
        const float hn  = GP(1, 0, w, 2, tj) + GP(1, 1, w, 2, tj);
        const float rg = 1.f / (1.f + __expf(-(ir + hr)));
        const float zg = 1.f / (1.f + __expf(-(iz + hz)));
        const float ng = tanhf(inn + rg * hn);
        hnew = (1.f - zg) * ng + zg * hol[w][tj];
        h_out[(size_t)(gR0 + w) * HH + tj] = hnew;
    }

    if (LAST) {   // readout fold: one scalar atomicAdd per block
        __syncthreads();                  // phase C mml reads complete
        if (w < 4) mml[w][tj] = hnew;
        __syncthreads();
        if (w == 0) {
            float v = (mml[0][tj] + mml[1][tj] + mml[2][tj] + mml[3][tj])
                      * (1.0f / NN) * Wout[tj];
#pragma unroll
            for (int off = 32; off >= 1; off >>= 1) v += __shfl_xor(v, off);
            if (tj == 0) atomicAdd(out + b, v);
        }
    }
#undef RED
#undef GP
}

extern "C" void kernel_launch(void* const* d_in, const int* in_sizes, int n_in,
                              void* d_out, int out_size, void* d_ws, size_t ws_size,
                              hipStream_t stream)
{
    const float* x     = (const float*)d_in[0];
    const float* W_enc = (const float*)d_in[1];
    const float* b_enc = (const float*)d_in[2];
    const float* W_e1  = (const float*)d_in[3];
    const float* b_e1  = (const float*)d_in[4];
    const float* W_e2  = (const float*)d_in[5];
    const float* b_e2  = (const float*)d_in[6];
    const float* W_msg = (const float*)d_in[7];
    const float* b_msg = (const float*)d_in[8];
    const float* W_ih  = (const float*)d_in[9];
    const float* b_ih  = (const float*)d_in[10];
    const float* W_hh  = (const float*)d_in[11];
    const float* b_hh  = (const float*)d_in[12];
    const float* W_out = (const float*)d_in[13];
    const float* b_out = (const float*)d_in[14];
    float* out = (float*)d_out;

    float* ws   = (float*)d_ws;
    float* h0   = ws;
    float* h1   = h0 + BB * NN * HH;
    float* zi   = h1 + BB * NN * HH;
    float* zjT2 = zi + BB * NN * HH;        // float2[B][32][N]
    float* adjw = zjT2 + BB * NN * HH;

    encode_kernel<<<BB * NN / 4, 256, 0, stream>>>(
        x, W_enc, b_enc, W_e1, b_e1, h0, zi, zjT2);

    adj_kernel<<<BB * (NN / 4), 512, 0, stream>>>(
        zi, zjT2, W_e2, b_e2, b_out, adjw, out);

    layer_kernel<0><<<BB * (NN / 4), 512, 0, stream>>>(
        adjw, h0, W_msg, b_msg, W_ih, b_ih, W_hh, b_hh, W_out, h1, out);
    layer_kernel<1><<<BB * (NN / 4), 512, 0, stream>>>(
        adjw, h1, W_msg + HH * HH, b_msg + HH,
        W_ih + HH * 3 * HH, b_ih + 3 * HH, W_hh + HH * 3 * HH, b_hh + 3 * HH,
        W_out, h0, out);
}